// Round 5
// baseline (254.413 us; speedup 1.0000x reference)
//
#include <hip/hip_runtime.h>
#include <hip/hip_bf16.h>

#define NPOS 4096
#define BB 2
#define KS 8   // k-split for PV pass
#define QS 8   // q-split for stats pass

typedef short v4s __attribute__((ext_vector_type(4)));
typedef float v4f __attribute__((ext_vector_type(4)));
typedef unsigned short ushort_t;

static __device__ __forceinline__ unsigned short f2bf(float f) {
    unsigned int u = __float_as_uint(f);
    return (unsigned short)((u + 0x7fffu + ((u >> 16) & 1u)) >> 16);
}

__device__ __forceinline__ float pe_val(int C, int c, int ch, int h, int w) {
    int blk = ch / c;
    int j = ch - blk * c;
    int half = c >> 1;
    int jj = (j < half) ? j : j - half;
    float freq = __expf(-(2.0f * jj / (float)c) * 9.210340371976184f); // ln(10000)
    int pos = (blk < 2) ? h : w;   // torch-broadcast quirk: blocks 0,1 -> y(=h), block 2 -> z(=w)
    float s = (float)pos * freq;
    return (j < half) ? __sinf(s) : __cosf(s);
}

__global__ void pe_add_kernel(const float* __restrict__ in, float* __restrict__ out, int C, int c) {
    int idx = blockIdx.x * 256 + threadIdx.x;
    int total = BB * C * NPOS;
    if (idx >= total) return;
    int n = idx & 4095;
    int ch = (idx >> 12) % C;
    int h = (n >> 4) & 15;
    int w = n & 15;
    out[idx] = in[idx] + pe_val(C, c, ch, h, w);
}

// conv1x1 + BN + ReLU, co-split x8.  in: (B,CI,N) -> out: (B,N,48)
template<int CI>
__global__ void proj_kernel(const float* __restrict__ in, const float* __restrict__ w,
                            const float* __restrict__ bias, const float* __restrict__ g,
                            const float* __restrict__ be, float* __restrict__ out) {
    int pc = blockIdx.x >> 3, cc = blockIdx.x & 7;
    int o0 = cc * 6;
    __shared__ float wl[6 * CI];
    __shared__ float sb[6], bb[6];
    int t = threadIdx.x;
    for (int i = t; i < 6 * CI; i += 256) {
        int o = i / CI, ci = i - o * CI;
        wl[i] = w[(size_t)(o0 + o) * CI + ci];
    }
    if (t < 6) {
        float s = g[o0 + t] * rsqrtf(1.0f + 1e-5f);
        sb[t] = s; bb[t] = bias[o0 + t] * s + be[o0 + t];
    }
    __syncthreads();
    int gn = pc * 256 + t;
    int b = gn >> 12;
    const float* ip = in + (size_t)b * CI * NPOS + (gn & 4095);
    float acc[6];
#pragma unroll
    for (int o = 0; o < 6; o++) acc[o] = 0.f;
#pragma unroll
    for (int ci = 0; ci < CI; ci++) {
        float v = ip[(size_t)ci * NPOS];
#pragma unroll
        for (int o = 0; o < 6; o++) acc[o] += v * wl[o * CI + ci];
    }
    float* op = out + (size_t)gn * 48 + o0;
#pragma unroll
    for (int o = 0; o < 6; o++) {
        float z = acc[o] * sb[o] + bb[o];
        op[o] = z > 0.f ? z : 0.f;
    }
}

// Q,K,V co-split x8.  grid = 3 grp * 32 pc * 8 cc = 768 blocks.
__global__ void qkv_kernel(const float* __restrict__ Y1, const float* __restrict__ S1,
                           const float* __restrict__ Wq, const float* __restrict__ Wk,
                           const float* __restrict__ Wv, ushort_t* __restrict__ Qb,
                           ushort_t* __restrict__ Kb, ushort_t* __restrict__ Vt) {
    int grp = blockIdx.x >> 8;
    int r = blockIdx.x & 255;
    int pc = r >> 3, cc = r & 7;
    int o0 = cc * 6;
    const float* in = (grp == 2) ? S1 : Y1;
    const float* w = (grp == 0) ? Wq : (grp == 1) ? Wk : Wv;
    __shared__ float wl[48 * 6];   // [d][o]
    int t = threadIdx.x;
    for (int i = t; i < 48 * 6; i += 256) {
        int d = i / 6, o = i - d * 6;
        wl[i] = w[(size_t)d * 48 + o0 + o];
    }
    __syncthreads();
    int gn = pc * 256 + t;
    const float* ip = in + (size_t)gn * 48;
    float acc[6];
#pragma unroll
    for (int o = 0; o < 6; o++) acc[o] = 0.f;
#pragma unroll
    for (int d = 0; d < 48; d++) {
        float v = ip[d];
#pragma unroll
        for (int o = 0; o < 6; o++) acc[o] += v * wl[d * 6 + o];
    }
    if (grp < 2) {
        ushort_t* op = (grp == 0 ? Qb : Kb) + (size_t)gn * 48 + o0;
#pragma unroll
        for (int o = 0; o < 6; o++) op[o] = f2bf(acc[o]);
    } else {
        int b = gn >> 12; int n = gn & 4095;
#pragma unroll
        for (int o = 0; o < 6; o++)
            Vt[((size_t)(b * 48 + o0 + o) << 12) + n] = f2bf(acc[o]);
    }
}

// Pass 1: column (over-q) exp-sum via swapped MFMA S^T = K*Q^T.
// No max subtraction: scores bounded << 80, fp32 exp is safe; softmax is
// shift-invariant so result identical.  1 exp per score, no serial fmax chain.
__global__ void attn_stats_mfma_kernel(const ushort_t* __restrict__ Qb,
                                       const ushort_t* __restrict__ Kb,
                                       float* __restrict__ ps) {
    int bid = blockIdx.x;
    int qs = bid & (QS - 1); int kb = (bid >> 3) & 63; int b = bid >> 9;
    int t = threadIdx.x; int wv = t >> 6; int lane = t & 63;
    int lr = lane & 15, g = lane >> 4;
    const float scale = 0.14433756729740643f;
    int key = kb * 64 + wv * 16 + lr;
    const ushort_t* krow = Kb + ((size_t)(b * NPOS + key)) * 48;
    v4s ka[3];
#pragma unroll
    for (int db = 0; db < 3; db++) ka[db] = *(const v4s*)(krow + 16 * db + 4 * g);
    float s[4];
#pragma unroll
    for (int r = 0; r < 4; r++) s[r] = 0.f;
    for (int qt = 0; qt < 512 / 16; qt++) {
        int q = qs * 512 + qt * 16 + lr;
        const ushort_t* qrow = Qb + ((size_t)(b * NPOS + q)) * 48;
        v4f acc = {0.f, 0.f, 0.f, 0.f};
        __builtin_amdgcn_s_setprio(1);
#pragma unroll
        for (int db = 0; db < 3; db++)
            acc = __builtin_amdgcn_mfma_f32_16x16x16bf16_1k(
                ka[db], *(const v4s*)(qrow + 16 * db + 4 * g), acc, 0, 0, 0);
        __builtin_amdgcn_s_setprio(0);
#pragma unroll
        for (int r = 0; r < 4; r++) s[r] += __expf(acc[r] * scale);
    }
#pragma unroll
    for (int off = 1; off < 16; off <<= 1)
#pragma unroll
        for (int r = 0; r < 4; r++) s[r] += __shfl_xor(s[r], off);
    if (lr == 0) {
        int idx = (b * QS + qs) * NPOS + kb * 64 + wv * 16 + 4 * g;
        v4f ss = {s[0], s[1], s[2], s[3]};
        *(v4f*)&ps[idx] = ss;
    }
}

__global__ void stats_reduce_kernel(const float* __restrict__ ps, float* __restrict__ colinv) {
    int idx = blockIdx.x * 128 + threadIdx.x;
    if (idx >= BB * NPOS) return;
    int b = idx >> 12; int k = idx & 4095;
    float s = 0.f;
#pragma unroll
    for (int qs = 0; qs < QS; qs++) s += ps[(size_t)(b * QS + qs) * NPOS + k];
    colinv[idx] = 1.0f / s;
}

// Pass 2: x = A*V via MFMA, swapped-MFMA chaining.  xpart layout (b,ks,q,48).
__global__ void attn_pv_mfma_kernel(const ushort_t* __restrict__ Qb,
                                    const ushort_t* __restrict__ Kb,
                                    const ushort_t* __restrict__ Vt,
                                    const float* __restrict__ colinv,
                                    float* __restrict__ xpart) {
    int bid = blockIdx.x;
    int ks = bid & (KS - 1); int qb = (bid >> 3) & 63; int b = bid >> 9;
    int t = threadIdx.x; int wv = t >> 6; int lane = t & 63;
    int lr = lane & 15, g = lane >> 4;
    const float scale = 0.14433756729740643f;
    int q0 = qb * 64 + wv * 16;
    const ushort_t* qrow = Qb + ((size_t)(b * NPOS + q0 + lr)) * 48;
    v4s qf[3];
#pragma unroll
    for (int db = 0; db < 3; db++) qf[db] = *(const v4s*)(qrow + 16 * db + 4 * g);
    v4f xacc[3];
#pragma unroll
    for (int nt = 0; nt < 3; nt++) xacc[nt] = (v4f){0.f, 0.f, 0.f, 0.f};
    for (int kt = 0; kt < 4096 / KS / 64; kt++) {
        int kb0 = ks * (4096 / KS) + kt * 64;
        v4s p[4];
#pragma unroll
        for (int tm = 0; tm < 4; tm++) {
            const ushort_t* krow = Kb + ((size_t)(b * NPOS + kb0 + 16 * tm + lr)) * 48;
            v4f acc = {0.f, 0.f, 0.f, 0.f};
            __builtin_amdgcn_s_setprio(1);
#pragma unroll
            for (int db = 0; db < 3; db++)
                acc = __builtin_amdgcn_mfma_f32_16x16x16bf16_1k(
                    *(const v4s*)(krow + 16 * db + 4 * g), qf[db], acc, 0, 0, 0);
            __builtin_amdgcn_s_setprio(0);
            int kc = b * NPOS + kb0 + 16 * tm + 4 * g;
            v4f ci = *(const v4f*)&colinv[kc];
            v4s pp;
#pragma unroll
            for (int r = 0; r < 4; r++)
                pp[r] = (short)f2bf(__expf(acc[r] * scale) * ci[r]);
            p[tm] = pp;
        }
        __builtin_amdgcn_s_setprio(1);
#pragma unroll
        for (int nt = 0; nt < 3; nt++) {
            const ushort_t* vrow = Vt + ((size_t)(b * 48 + 16 * nt + lr) << 12) + kb0;
#pragma unroll
            for (int tm = 0; tm < 4; tm++)
                xacc[nt] = __builtin_amdgcn_mfma_f32_16x16x16bf16_1k(
                    p[tm], *(const v4s*)(vrow + 16 * tm + 4 * g), xacc[nt], 0, 0, 0);
        }
        __builtin_amdgcn_s_setprio(0);
    }
    // lane: d = 16nt+lr, q = q0+4g+r -> xpart[((b*KS+ks)*4096 + q)*48 + d]
#pragma unroll
    for (int nt = 0; nt < 3; nt++)
#pragma unroll
        for (int r = 0; r < 4; r++)
            xpart[(((size_t)(b * KS + ks) << 12) + q0 + 4 * g + r) * 48 + 16 * nt + lr] = xacc[nt][r];
}

// Reduce x partials + conv1x1(w_o) + BN + ReLU, * S_pe -> out ch [0,48).  co-split x8.
__global__ void z_out_kernel(const float* __restrict__ xpart, const float* __restrict__ w_o,
                             const float* __restrict__ b_o, const float* __restrict__ g_o,
                             const float* __restrict__ be_o, const float* __restrict__ S_pe,
                             float* __restrict__ out) {
    int pc = blockIdx.x >> 3, cc = blockIdx.x & 7;
    int o0 = cc * 6;
    __shared__ float wl[6 * 48];
    __shared__ float sb[6], bb[6];
    int t = threadIdx.x;
    for (int i = t; i < 6 * 48; i += 256) {
        int o = i / 48, d = i - o * 48;
        wl[i] = w_o[(size_t)(o0 + o) * 48 + d];
    }
    if (t < 6) {
        float s = g_o[o0 + t] * rsqrtf(1.f + 1e-5f);
        sb[t] = s; bb[t] = b_o[o0 + t] * s + be_o[o0 + t];
    }
    __syncthreads();
    int gn = pc * 256 + t;
    int b = gn >> 12; int n = gn & 4095;
    float x[48];
#pragma unroll
    for (int d = 0; d < 48; d++) x[d] = 0.f;
#pragma unroll
    for (int ks = 0; ks < KS; ks++) {
        const v4f* p = (const v4f*)(xpart + (((size_t)(b * KS + ks) << 12) + n) * 48);
#pragma unroll
        for (int d4 = 0; d4 < 12; d4++) {
            v4f v = p[d4];
#pragma unroll
            for (int j = 0; j < 4; j++) x[d4 * 4 + j] += v[j];
        }
    }
#pragma unroll
    for (int o = 0; o < 6; o++) {
        float acc = 0.f;
#pragma unroll
        for (int d = 0; d < 48; d++) acc += wl[o * 48 + d] * x[d];
        float z = acc * sb[o] + bb[o];
        z = z > 0.f ? z : 0.f;
        out[((size_t)b * 96 + o0 + o) * NPOS + n] = z * S_pe[((size_t)b * 48 + o0 + o) * NPOS + n];
    }
}

// ---- conv3d via implicit-GEMM MFMA ----

// Y_pe (B,96,4096) fp32 -> Y_pad (B,18,18,18,96) bf16, halo zeroed inline
__global__ void pad_build_kernel(const float* __restrict__ Y_pe, ushort_t* __restrict__ Ypad) {
    int idx = blockIdx.x * 256 + threadIdx.x;   // over B*5832 cells * 24 ci4
    if (idx >= BB * 5832 * 24) return;
    int ci4 = idx % 24;
    int cell = idx / 24;
    int wp = cell % 18; int c2 = cell / 18;
    int hp = c2 % 18; int c3 = c2 / 18;
    int zp = c3 % 18; int b = c3 / 18;
    ushort_t pk[4] = {0, 0, 0, 0};
    if (zp >= 1 && zp <= 16 && hp >= 1 && hp <= 16 && wp >= 1 && wp <= 16) {
        int n = (zp - 1) * 256 + (hp - 1) * 16 + (wp - 1);
#pragma unroll
        for (int j = 0; j < 4; j++)
            pk[j] = f2bf(Y_pe[((size_t)(b * 96 + ci4 * 4 + j) << 12) + n]);
    }
    *(v4s*)&Ypad[(size_t)idx * 4] = *(v4s*)pk;
}

// w3 (96co, 96ci, 27tap) fp32 -> wr [27][96co][96ci] bf16
__global__ void w3_repack_kernel(const float* __restrict__ w3, ushort_t* __restrict__ wr) {
    int idx = blockIdx.x * 256 + threadIdx.x;
    if (idx >= 27 * 96 * 96) return;
    int ci = idx % 96;
    int t2 = idx / 96;
    int co = t2 % 96;
    int tap = t2 / 96;
    wr[idx] = f2bf(w3[(size_t)(co * 96 + ci) * 27 + tap]);
}

// implicit-GEMM conv.  Y3 out layout: position-major (B,4096,96) fp32.
__global__ void conv3d_mfma_kernel(const ushort_t* __restrict__ Ypad,
                                   const ushort_t* __restrict__ wr,
                                   const float* __restrict__ b3,
                                   float* __restrict__ Y3) {
    int bid = blockIdx.x;
    int b = bid / 384;
    int r = bid % 384;
    int cot = r % 6;
    int zhq = r / 6;                 // 0..63
    int t = threadIdx.x; int wv = t >> 6; int lane = t & 63;
    int z = zhq >> 2;
    int h = (zhq & 3) * 4 + wv;
    int lr = lane & 15, g4 = (lane >> 4) * 4;
    float bv = b3[cot * 16 + lr];
    v4f acc = {bv, bv, bv, bv};
    for (int kd = 0; kd < 3; kd++) {
        for (int kh = 0; kh < 3; kh++) {
            const ushort_t* arow = Ypad + (((size_t)(b * 18 + z + kd) * 18 + h + kh) * 18 + lr) * 96 + g4;
            int tap0 = (kd * 3 + kh) * 3;
#pragma unroll
            for (int kw = 0; kw < 3; kw++) {
                const ushort_t* abase = arow + (size_t)kw * 96;
                const ushort_t* bbase = wr + ((size_t)((tap0 + kw) * 96 + cot * 16 + lr)) * 96 + g4;
                __builtin_amdgcn_s_setprio(1);
#pragma unroll
                for (int cich = 0; cich < 6; cich++)
                    acc = __builtin_amdgcn_mfma_f32_16x16x16bf16_1k(
                        *(const v4s*)(abase + cich * 16),
                        *(const v4s*)(bbase + cich * 16), acc, 0, 0, 0);
                __builtin_amdgcn_s_setprio(0);
            }
        }
    }
    int pos = z * 256 + h * 16 + g4;
#pragma unroll
    for (int r2 = 0; r2 < 4; r2++)
        Y3[(((size_t)b << 12) + pos + r2) * 96 + cot * 16 + lr] = acc[r2];
}

// conv1x1(w_y2) + BN + ReLU on Y3 (B,4096,96) -> out ch [48,96).  co-split x8.
__global__ void y2_out_kernel(const float* __restrict__ Y3, const float* __restrict__ w_y2,
                              const float* __restrict__ b_y2, const float* __restrict__ g_y2,
                              const float* __restrict__ be_y2, float* __restrict__ out) {
    int pc = blockIdx.x >> 3, cc = blockIdx.x & 7;
    int o0 = cc * 6;
    __shared__ float wl[6 * 96];
    __shared__ float sb[6], bb[6];
    int t = threadIdx.x;
    for (int i = t; i < 6 * 96; i += 256) {
        int o = i / 96, ci = i - o * 96;
        wl[i] = w_y2[(size_t)(o0 + o) * 96 + ci];
    }
    if (t < 6) {
        float s = g_y2[o0 + t] * rsqrtf(1.f + 1e-5f);
        sb[t] = s; bb[t] = b_y2[o0 + t] * s + be_y2[o0 + t];
    }
    __syncthreads();
    int gn = pc * 256 + t;
    int b = gn >> 12; int n = gn & 4095;
    const v4f* ip = (const v4f*)(Y3 + (size_t)gn * 96);
    float acc[6];
#pragma unroll
    for (int o = 0; o < 6; o++) acc[o] = 0.f;
#pragma unroll
    for (int c4 = 0; c4 < 24; c4++) {
        v4f v = ip[c4];
#pragma unroll
        for (int j = 0; j < 4; j++)
#pragma unroll
            for (int o = 0; o < 6; o++) acc[o] += v[j] * wl[o * 96 + c4 * 4 + j];
    }
#pragma unroll
    for (int o = 0; o < 6; o++) {
        float z = acc[o] * sb[o] + bb[o];
        out[((size_t)b * 96 + 48 + o0 + o) * NPOS + n] = z > 0.f ? z : 0.f;
    }
}

extern "C" void kernel_launch(void* const* d_in, const int* in_sizes, int n_in,
                              void* d_out, int out_size, void* d_ws, size_t ws_size,
                              hipStream_t stream) {
    const float* Y    = (const float*)d_in[0];
    const float* S    = (const float*)d_in[1];
    const float* w_s  = (const float*)d_in[2];
    const float* b_s  = (const float*)d_in[3];
    const float* g_s  = (const float*)d_in[4];
    const float* be_s = (const float*)d_in[5];
    const float* w_y  = (const float*)d_in[6];
    const float* b_y  = (const float*)d_in[7];
    const float* g_y  = (const float*)d_in[8];
    const float* be_y = (const float*)d_in[9];
    const float* Wq   = (const float*)d_in[10];
    const float* Wk   = (const float*)d_in[11];
    const float* Wv   = (const float*)d_in[12];
    const float* w_o  = (const float*)d_in[13];
    const float* b_o  = (const float*)d_in[14];
    const float* g_o  = (const float*)d_in[15];
    const float* be_o = (const float*)d_in[16];
    const float* w3   = (const float*)d_in[17];
    const float* b3   = (const float*)d_in[18];
    const float* w_y2 = (const float*)d_in[19];
    const float* b_y2 = (const float*)d_in[20];
    const float* g_y2 = (const float*)d_in[21];
    const float* be_y2= (const float*)d_in[22];
    float* out = (float*)d_out;

    float* ws = (float*)d_ws;
    float* S_pe   = ws;                        // 393216
    float* Y_pe   = ws + 393216;               // 786432
    float* S1     = ws + 1179648;              // 393216
    float* Y1     = ws + 1572864;              // 393216
    ushort_t* Qb  = (ushort_t*)(ws + 1966080); // 196608 f
    ushort_t* Kb  = (ushort_t*)(ws + 2162688); // 196608 f
    ushort_t* Vt  = (ushort_t*)(ws + 2359296); // 196608 f
    float* ps     = ws + 2555904;              // 2*QS*4096 = 65536
    float* colinv = ws + 2621440;              // 8192
    float* xpart  = ws + 2629632;              // (b,ks,q,48) = 2*8*4096*48 = 3145728
    float* Y3     = ws + 5775360;              // (b,n,96) 786432
    ushort_t* Ypad= (ushort_t*)(ws + 6561792); // 559872 f
    ushort_t* wr  = (ushort_t*)(ws + 7121664); // 124416 f

    // conv3d weight repack (independent)
    w3_repack_kernel<<<972, 256, 0, stream>>>(w3, wr);
    // 1. positional encodings
    pe_add_kernel<<<1536, 256, 0, stream>>>(S, S_pe, 48, 16);
    pe_add_kernel<<<3072, 256, 0, stream>>>(Y, Y_pe, 96, 32);
    // conv3d input pad (bf16, halo zeroed inline)
    pad_build_kernel<<<1094, 256, 0, stream>>>(Y_pe, Ypad);
    // 2. projections (conv1x1 + BN + ReLU) -> (B,N,48), co-split x8
    proj_kernel<48><<<256, 256, 0, stream>>>(S_pe, w_s, b_s, g_s, be_s, S1);
    proj_kernel<96><<<256, 256, 0, stream>>>(Y_pe, w_y, b_y, g_y, be_y, Y1);
    // 3. Q, K row-major bf16; V transposed bf16, co-split x8
    qkv_kernel<<<768, 256, 0, stream>>>(Y1, S1, Wq, Wk, Wv, Qb, Kb, Vt);
    // 4. column exp-sum (softmax over q, per key k; no max — shift-invariant), MFMA
    attn_stats_mfma_kernel<<<BB * 64 * QS, 256, 0, stream>>>(Qb, Kb, ps);
    stats_reduce_kernel<<<64, 128, 0, stream>>>(ps, colinv);
    // 5. x = A @ V partials, MFMA
    attn_pv_mfma_kernel<<<BB * 64 * KS, 256, 0, stream>>>(Qb, Kb, Vt, colinv, xpart);
    // 6. 3x3x3 conv branch, implicit-GEMM MFMA
    conv3d_mfma_kernel<<<768, 256, 0, stream>>>(Ypad, wr, b3, Y3);
    // 7. outputs, co-split x8
    z_out_kernel<<<256, 256, 0, stream>>>(xpart, w_o, b_o, g_o, be_o, S_pe, out);
    y2_out_kernel<<<256, 256, 0, stream>>>(Y3, w_y2, b_y2, g_y2, be_y2, out);
}

// Round 6
// 197.876 us; speedup vs baseline: 1.2857x; 1.2857x over previous
//
#include <hip/hip_runtime.h>
#include <hip/hip_bf16.h>

#define NPOS 4096
#define BB 2
#define KS 16  // k-split for PV pass (256 keys per chunk)
#define QS 16  // q-split for stats pass (256 q per chunk)

typedef short v4s __attribute__((ext_vector_type(4)));
typedef float v4f __attribute__((ext_vector_type(4)));
typedef unsigned short ushort_t;

static __device__ __forceinline__ unsigned short f2bf(float f) {
    unsigned int u = __float_as_uint(f);
    return (unsigned short)((u + 0x7fffu + ((u >> 16) & 1u)) >> 16);
}
static __device__ __forceinline__ float bf2f(ushort_t s) {
    return __uint_as_float(((unsigned int)s) << 16);
}

__device__ __forceinline__ float pe_val(int C, int c, int ch, int h, int w) {
    int blk = ch / c;
    int j = ch - blk * c;
    int half = c >> 1;
    int jj = (j < half) ? j : j - half;
    float freq = __expf(-(2.0f * jj / (float)c) * 9.210340371976184f); // ln(10000)
    int pos = (blk < 2) ? h : w;   // torch-broadcast quirk: blocks 0,1 -> y(=h), block 2 -> z(=w)
    float s = (float)pos * freq;
    return (j < half) ? __sinf(s) : __cosf(s);
}

__global__ void pe_add_kernel(const float* __restrict__ in, float* __restrict__ out, int C, int c) {
    int idx = blockIdx.x * 256 + threadIdx.x;
    int total = BB * C * NPOS;
    if (idx >= total) return;
    int n = idx & 4095;
    int ch = (idx >> 12) % C;
    int h = (n >> 4) & 15;
    int w = n & 15;
    out[idx] = in[idx] + pe_val(C, c, ch, h, w);
}

// conv1x1 + BN + ReLU, co-split x8.  in: (B,CI,N) -> out: (B,N,48)
template<int CI>
__global__ void proj_kernel(const float* __restrict__ in, const float* __restrict__ w,
                            const float* __restrict__ bias, const float* __restrict__ g,
                            const float* __restrict__ be, float* __restrict__ out) {
    int pc = blockIdx.x >> 3, cc = blockIdx.x & 7;
    int o0 = cc * 6;
    __shared__ float wl[6 * CI];
    __shared__ float sb[6], bb[6];
    int t = threadIdx.x;
    for (int i = t; i < 6 * CI; i += 256) {
        int o = i / CI, ci = i - o * CI;
        wl[i] = w[(size_t)(o0 + o) * CI + ci];
    }
    if (t < 6) {
        float s = g[o0 + t] * rsqrtf(1.0f + 1e-5f);
        sb[t] = s; bb[t] = bias[o0 + t] * s + be[o0 + t];
    }
    __syncthreads();
    int gn = pc * 256 + t;
    int b = gn >> 12;
    const float* ip = in + (size_t)b * CI * NPOS + (gn & 4095);
    float acc[6];
#pragma unroll
    for (int o = 0; o < 6; o++) acc[o] = 0.f;
#pragma unroll
    for (int ci = 0; ci < CI; ci++) {
        float v = ip[(size_t)ci * NPOS];
#pragma unroll
        for (int o = 0; o < 6; o++) acc[o] += v * wl[o * CI + ci];
    }
    float* op = out + (size_t)gn * 48 + o0;
#pragma unroll
    for (int o = 0; o < 6; o++) {
        float z = acc[o] * sb[o] + bb[o];
        op[o] = z > 0.f ? z : 0.f;
    }
}

// Q,K,V co-split x8.  grid = 3 grp * 32 pc * 8 cc = 768 blocks.
__global__ void qkv_kernel(const float* __restrict__ Y1, const float* __restrict__ S1,
                           const float* __restrict__ Wq, const float* __restrict__ Wk,
                           const float* __restrict__ Wv, ushort_t* __restrict__ Qb,
                           ushort_t* __restrict__ Kb, ushort_t* __restrict__ Vt) {
    int grp = blockIdx.x >> 8;
    int r = blockIdx.x & 255;
    int pc = r >> 3, cc = r & 7;
    int o0 = cc * 6;
    const float* in = (grp == 2) ? S1 : Y1;
    const float* w = (grp == 0) ? Wq : (grp == 1) ? Wk : Wv;
    __shared__ float wl[48 * 6];   // [d][o]
    int t = threadIdx.x;
    for (int i = t; i < 48 * 6; i += 256) {
        int d = i / 6, o = i - d * 6;
        wl[i] = w[(size_t)d * 48 + o0 + o];
    }
    __syncthreads();
    int gn = pc * 256 + t;
    const float* ip = in + (size_t)gn * 48;
    float acc[6];
#pragma unroll
    for (int o = 0; o < 6; o++) acc[o] = 0.f;
#pragma unroll
    for (int d = 0; d < 48; d++) {
        float v = ip[d];
#pragma unroll
        for (int o = 0; o < 6; o++) acc[o] += v * wl[d * 6 + o];
    }
    if (grp < 2) {
        ushort_t* op = (grp == 0 ? Qb : Kb) + (size_t)gn * 48 + o0;
#pragma unroll
        for (int o = 0; o < 6; o++) op[o] = f2bf(acc[o]);
    } else {
        int b = gn >> 12; int n = gn & 4095;
#pragma unroll
        for (int o = 0; o < 6; o++)
            Vt[((size_t)(b * 48 + o0 + o) << 12) + n] = f2bf(acc[o]);
    }
}

// Pass 1: column (over-q) exp-sum.  Wave owns 64 keys (4 key-tiles, A-frags in
// regs), streams 256 q; each Q-fragment load feeds 12 MFMAs (4x amortized).
// grid: b(2) x kb(16) x qs(16) = 512 blocks.
__global__ void attn_stats_mfma_kernel(const ushort_t* __restrict__ Qb,
                                       const ushort_t* __restrict__ Kb,
                                       float* __restrict__ ps) {
    int bid = blockIdx.x;
    int qs = bid & 15; int kb = (bid >> 4) & 15; int b = bid >> 8;
    int t = threadIdx.x; int wv = t >> 6; int lane = t & 63;
    int lr = lane & 15, g = lane >> 4;
    const float scale = 0.14433756729740643f;
    int key0 = kb * 256 + wv * 64;
    v4s ka[4][3];
#pragma unroll
    for (int kt = 0; kt < 4; kt++) {
        const ushort_t* krow = Kb + ((size_t)(b * NPOS + key0 + kt * 16 + lr)) * 48;
#pragma unroll
        for (int db = 0; db < 3; db++) ka[kt][db] = *(const v4s*)(krow + 16 * db + 4 * g);
    }
    float s[4][4];
#pragma unroll
    for (int kt = 0; kt < 4; kt++)
#pragma unroll
        for (int r = 0; r < 4; r++) s[kt][r] = 0.f;
    for (int qt = 0; qt < 16; qt++) {
        int q = qs * 256 + qt * 16 + lr;
        const ushort_t* qrow = Qb + ((size_t)(b * NPOS + q)) * 48;
        v4s qf0 = *(const v4s*)(qrow + 4 * g);
        v4s qf1 = *(const v4s*)(qrow + 16 + 4 * g);
        v4s qf2 = *(const v4s*)(qrow + 32 + 4 * g);
#pragma unroll
        for (int kt = 0; kt < 4; kt++) {
            v4f acc = {0.f, 0.f, 0.f, 0.f};
            acc = __builtin_amdgcn_mfma_f32_16x16x16bf16_1k(ka[kt][0], qf0, acc, 0, 0, 0);
            acc = __builtin_amdgcn_mfma_f32_16x16x16bf16_1k(ka[kt][1], qf1, acc, 0, 0, 0);
            acc = __builtin_amdgcn_mfma_f32_16x16x16bf16_1k(ka[kt][2], qf2, acc, 0, 0, 0);
#pragma unroll
            for (int r = 0; r < 4; r++) s[kt][r] += __expf(acc[r] * scale);
        }
    }
#pragma unroll
    for (int off = 1; off < 16; off <<= 1)
#pragma unroll
        for (int kt = 0; kt < 4; kt++)
#pragma unroll
            for (int r = 0; r < 4; r++) s[kt][r] += __shfl_xor(s[kt][r], off);
    if (lr == 0) {
#pragma unroll
        for (int kt = 0; kt < 4; kt++) {
            int idx = (b * QS + qs) * NPOS + key0 + kt * 16 + 4 * g;
            v4f ss = {s[kt][0], s[kt][1], s[kt][2], s[kt][3]};
            *(v4f*)&ps[idx] = ss;
        }
    }
}

__global__ void stats_reduce_kernel(const float* __restrict__ ps, float* __restrict__ colinv) {
    int idx = blockIdx.x * 128 + threadIdx.x;
    if (idx >= BB * NPOS) return;
    int b = idx >> 12; int k = idx & 4095;
    float s = 0.f;
#pragma unroll
    for (int qs = 0; qs < QS; qs++) s += ps[(size_t)(b * QS + qs) * NPOS + k];
    colinv[idx] = 1.0f / s;
}

// V' = V * colinv (per-key scale), in-place on Vt (b,48,4096).
__global__ void vscale_kernel(ushort_t* __restrict__ Vt, const float* __restrict__ colinv) {
    int idx = blockIdx.x * 256 + threadIdx.x;   // over B*48*1024
    if (idx >= BB * 48 * 1024) return;
    int n4 = idx & 1023; int rest = idx >> 10;
    int d = rest % 48; int b = rest / 48;
    ushort_t* vp = Vt + ((size_t)(b * 48 + d) << 12) + n4 * 4;
    v4s v = *(v4s*)vp;
    v4f ci = *(const v4f*)&colinv[(b << 12) + n4 * 4];
    v4s o;
#pragma unroll
    for (int j = 0; j < 4; j++) o[j] = (short)f2bf(bf2f((ushort_t)v[j]) * ci[j]);
    *(v4s*)vp = o;
}

// Pass 2: x = E * V' via MFMA (V pre-scaled by 1/Z).  Wave owns 64 q (4 q-tiles,
// B-frags in regs), streams 256 keys; each K/V fragment feeds 4x more MFMA.
// grid: b(2) x qb(16) x ks(16) = 512 blocks.  xpart bf16 (b,ks,q,48).
__global__ void attn_pv_mfma_kernel(const ushort_t* __restrict__ Qb,
                                    const ushort_t* __restrict__ Kb,
                                    const ushort_t* __restrict__ Vt,
                                    ushort_t* __restrict__ xpart) {
    int bid = blockIdx.x;
    int ks = bid & 15; int qb = (bid >> 4) & 15; int b = bid >> 8;
    int t = threadIdx.x; int wv = t >> 6; int lane = t & 63;
    int lr = lane & 15, g = lane >> 4;
    const float scale = 0.14433756729740643f;
    int q0 = qb * 256 + wv * 64;
    v4s qf[4][3];
#pragma unroll
    for (int qt = 0; qt < 4; qt++) {
        const ushort_t* qrow = Qb + ((size_t)(b * NPOS + q0 + qt * 16 + lr)) * 48;
#pragma unroll
        for (int db = 0; db < 3; db++) qf[qt][db] = *(const v4s*)(qrow + 16 * db + 4 * g);
    }
    v4f xacc[4][3];
#pragma unroll
    for (int qt = 0; qt < 4; qt++)
#pragma unroll
        for (int nt = 0; nt < 3; nt++) xacc[qt][nt] = (v4f){0.f, 0.f, 0.f, 0.f};
    for (int kt = 0; kt < 4; kt++) {
        int kb0 = ks * 256 + kt * 64;
        v4s p[4][4];   // [tm][qt]
#pragma unroll
        for (int tm = 0; tm < 4; tm++) {
            const ushort_t* krow = Kb + ((size_t)(b * NPOS + kb0 + 16 * tm + lr)) * 48;
            v4s ka0 = *(const v4s*)(krow + 4 * g);
            v4s ka1 = *(const v4s*)(krow + 16 + 4 * g);
            v4s ka2 = *(const v4s*)(krow + 32 + 4 * g);
#pragma unroll
            for (int qt = 0; qt < 4; qt++) {
                v4f acc = {0.f, 0.f, 0.f, 0.f};
                acc = __builtin_amdgcn_mfma_f32_16x16x16bf16_1k(ka0, qf[qt][0], acc, 0, 0, 0);
                acc = __builtin_amdgcn_mfma_f32_16x16x16bf16_1k(ka1, qf[qt][1], acc, 0, 0, 0);
                acc = __builtin_amdgcn_mfma_f32_16x16x16bf16_1k(ka2, qf[qt][2], acc, 0, 0, 0);
                v4s pp;
#pragma unroll
                for (int r = 0; r < 4; r++)
                    pp[r] = (short)f2bf(__expf(acc[r] * scale));
                p[tm][qt] = pp;
            }
        }
#pragma unroll
        for (int nt = 0; nt < 3; nt++) {
            const ushort_t* vrow = Vt + ((size_t)(b * 48 + 16 * nt + lr) << 12) + kb0;
#pragma unroll
            for (int tm = 0; tm < 4; tm++) {
                v4s vf = *(const v4s*)(vrow + 16 * tm + 4 * g);
#pragma unroll
                for (int qt = 0; qt < 4; qt++)
                    xacc[qt][nt] = __builtin_amdgcn_mfma_f32_16x16x16bf16_1k(
                        p[tm][qt], vf, xacc[qt][nt], 0, 0, 0);
            }
        }
    }
    // lane: d = 16nt+lr, q = q0+qt*16+4g+r -> xpart[((b*KS+ks)*4096 + q)*48 + d]
#pragma unroll
    for (int qt = 0; qt < 4; qt++)
#pragma unroll
        for (int nt = 0; nt < 3; nt++)
#pragma unroll
            for (int r = 0; r < 4; r++)
                xpart[(((size_t)(b * KS + ks) << 12) + q0 + qt * 16 + 4 * g + r) * 48 + 16 * nt + lr] =
                    f2bf(xacc[qt][nt][r]);
}

// Reduce x partials (bf16) + conv1x1(w_o) + BN + ReLU, * S_pe -> out ch [0,48).
__global__ void z_out_kernel(const ushort_t* __restrict__ xpart, const float* __restrict__ w_o,
                             const float* __restrict__ b_o, const float* __restrict__ g_o,
                             const float* __restrict__ be_o, const float* __restrict__ S_pe,
                             float* __restrict__ out) {
    int pc = blockIdx.x >> 3, cc = blockIdx.x & 7;
    int o0 = cc * 6;
    __shared__ float wl[6 * 48];
    __shared__ float sb[6], bb[6];
    int t = threadIdx.x;
    for (int i = t; i < 6 * 48; i += 256) {
        int o = i / 48, d = i - o * 48;
        wl[i] = w_o[(size_t)(o0 + o) * 48 + d];
    }
    if (t < 6) {
        float s = g_o[o0 + t] * rsqrtf(1.f + 1e-5f);
        sb[t] = s; bb[t] = b_o[o0 + t] * s + be_o[o0 + t];
    }
    __syncthreads();
    int gn = pc * 256 + t;
    int b = gn >> 12; int n = gn & 4095;
    float x[48];
#pragma unroll
    for (int d = 0; d < 48; d++) x[d] = 0.f;
#pragma unroll
    for (int ks = 0; ks < KS; ks++) {
        const v4s* p = (const v4s*)(xpart + (((size_t)(b * KS + ks) << 12) + n) * 48);
#pragma unroll
        for (int d4 = 0; d4 < 12; d4++) {
            v4s v = p[d4];
#pragma unroll
            for (int j = 0; j < 4; j++) x[d4 * 4 + j] += bf2f((ushort_t)v[j]);
        }
    }
#pragma unroll
    for (int o = 0; o < 6; o++) {
        float acc = 0.f;
#pragma unroll
        for (int d = 0; d < 48; d++) acc += wl[o * 48 + d] * x[d];
        float z = acc * sb[o] + bb[o];
        z = z > 0.f ? z : 0.f;
        out[((size_t)b * 96 + o0 + o) * NPOS + n] = z * S_pe[((size_t)b * 48 + o0 + o) * NPOS + n];
    }
}

// ---- conv3d via implicit-GEMM MFMA ----

// Y_pe (B,96,4096) fp32 -> Y_pad (B,18,18,18,96) bf16, halo zeroed inline
__global__ void pad_build_kernel(const float* __restrict__ Y_pe, ushort_t* __restrict__ Ypad) {
    int idx = blockIdx.x * 256 + threadIdx.x;   // over B*5832 cells * 24 ci4
    if (idx >= BB * 5832 * 24) return;
    int ci4 = idx % 24;
    int cell = idx / 24;
    int wp = cell % 18; int c2 = cell / 18;
    int hp = c2 % 18; int c3 = c2 / 18;
    int zp = c3 % 18; int b = c3 / 18;
    ushort_t pk[4] = {0, 0, 0, 0};
    if (zp >= 1 && zp <= 16 && hp >= 1 && hp <= 16 && wp >= 1 && wp <= 16) {
        int n = (zp - 1) * 256 + (hp - 1) * 16 + (wp - 1);
#pragma unroll
        for (int j = 0; j < 4; j++)
            pk[j] = f2bf(Y_pe[((size_t)(b * 96 + ci4 * 4 + j) << 12) + n]);
    }
    *(v4s*)&Ypad[(size_t)idx * 4] = *(v4s*)pk;
}

// w3 (96co, 96ci, 27tap) fp32 -> wr [27][96co][96ci] bf16
__global__ void w3_repack_kernel(const float* __restrict__ w3, ushort_t* __restrict__ wr) {
    int idx = blockIdx.x * 256 + threadIdx.x;
    if (idx >= 27 * 96 * 96) return;
    int ci = idx % 96;
    int t2 = idx / 96;
    int co = t2 % 96;
    int tap = t2 / 96;
    wr[idx] = f2bf(w3[(size_t)(co * 96 + ci) * 27 + tap]);
}

// implicit-GEMM conv.  Y3 out layout: position-major (B,4096,96) fp32.
__global__ void conv3d_mfma_kernel(const ushort_t* __restrict__ Ypad,
                                   const ushort_t* __restrict__ wr,
                                   const float* __restrict__ b3,
                                   float* __restrict__ Y3) {
    int bid = blockIdx.x;
    int b = bid / 384;
    int r = bid % 384;
    int cot = r % 6;
    int zhq = r / 6;                 // 0..63
    int t = threadIdx.x; int wv = t >> 6; int lane = t & 63;
    int z = zhq >> 2;
    int h = (zhq & 3) * 4 + wv;
    int lr = lane & 15, g4 = (lane >> 4) * 4;
    float bv = b3[cot * 16 + lr];
    v4f acc = {bv, bv, bv, bv};
    for (int kd = 0; kd < 3; kd++) {
        for (int kh = 0; kh < 3; kh++) {
            const ushort_t* arow = Ypad + (((size_t)(b * 18 + z + kd) * 18 + h + kh) * 18 + lr) * 96 + g4;
            int tap0 = (kd * 3 + kh) * 3;
#pragma unroll
            for (int kw = 0; kw < 3; kw++) {
                const ushort_t* abase = arow + (size_t)kw * 96;
                const ushort_t* bbase = wr + ((size_t)((tap0 + kw) * 96 + cot * 16 + lr)) * 96 + g4;
#pragma unroll
                for (int cich = 0; cich < 6; cich++)
                    acc = __builtin_amdgcn_mfma_f32_16x16x16bf16_1k(
                        *(const v4s*)(abase + cich * 16),
                        *(const v4s*)(bbase + cich * 16), acc, 0, 0, 0);
            }
        }
    }
    int pos = z * 256 + h * 16 + g4;
#pragma unroll
    for (int r2 = 0; r2 < 4; r2++)
        Y3[(((size_t)b << 12) + pos + r2) * 96 + cot * 16 + lr] = acc[r2];
}

// conv1x1(w_y2) + BN + ReLU on Y3 (B,4096,96) -> out ch [48,96).  co-split x8.
__global__ void y2_out_kernel(const float* __restrict__ Y3, const float* __restrict__ w_y2,
                              const float* __restrict__ b_y2, const float* __restrict__ g_y2,
                              const float* __restrict__ be_y2, float* __restrict__ out) {
    int pc = blockIdx.x >> 3, cc = blockIdx.x & 7;
    int o0 = cc * 6;
    __shared__ float wl[6 * 96];
    __shared__ float sb[6], bb[6];
    int t = threadIdx.x;
    for (int i = t; i < 6 * 96; i += 256) {
        int o = i / 96, ci = i - o * 96;
        wl[i] = w_y2[(size_t)(o0 + o) * 96 + ci];
    }
    if (t < 6) {
        float s = g_y2[o0 + t] * rsqrtf(1.f + 1e-5f);
        sb[t] = s; bb[t] = b_y2[o0 + t] * s + be_y2[o0 + t];
    }
    __syncthreads();
    int gn = pc * 256 + t;
    int b = gn >> 12; int n = gn & 4095;
    const v4f* ip = (const v4f*)(Y3 + (size_t)gn * 96);
    float acc[6];
#pragma unroll
    for (int o = 0; o < 6; o++) acc[o] = 0.f;
#pragma unroll
    for (int c4 = 0; c4 < 24; c4++) {
        v4f v = ip[c4];
#pragma unroll
        for (int j = 0; j < 4; j++)
#pragma unroll
            for (int o = 0; o < 6; o++) acc[o] += v[j] * wl[o * 96 + c4 * 4 + j];
    }
#pragma unroll
    for (int o = 0; o < 6; o++) {
        float z = acc[o] * sb[o] + bb[o];
        out[((size_t)b * 96 + 48 + o0 + o) * NPOS + n] = z > 0.f ? z : 0.f;
    }
}

extern "C" void kernel_launch(void* const* d_in, const int* in_sizes, int n_in,
                              void* d_out, int out_size, void* d_ws, size_t ws_size,
                              hipStream_t stream) {
    const float* Y    = (const float*)d_in[0];
    const float* S    = (const float*)d_in[1];
    const float* w_s  = (const float*)d_in[2];
    const float* b_s  = (const float*)d_in[3];
    const float* g_s  = (const float*)d_in[4];
    const float* be_s = (const float*)d_in[5];
    const float* w_y  = (const float*)d_in[6];
    const float* b_y  = (const float*)d_in[7];
    const float* g_y  = (const float*)d_in[8];
    const float* be_y = (const float*)d_in[9];
    const float* Wq   = (const float*)d_in[10];
    const float* Wk   = (const float*)d_in[11];
    const float* Wv   = (const float*)d_in[12];
    const float* w_o  = (const float*)d_in[13];
    const float* b_o  = (const float*)d_in[14];
    const float* g_o  = (const float*)d_in[15];
    const float* be_o = (const float*)d_in[16];
    const float* w3   = (const float*)d_in[17];
    const float* b3   = (const float*)d_in[18];
    const float* w_y2 = (const float*)d_in[19];
    const float* b_y2 = (const float*)d_in[20];
    const float* g_y2 = (const float*)d_in[21];
    const float* be_y2= (const float*)d_in[22];
    float* out = (float*)d_out;

    float* ws = (float*)d_ws;
    float* S_pe   = ws;                        // 393216
    float* Y_pe   = ws + 393216;               // 786432
    float* S1     = ws + 1179648;              // 393216
    float* Y1     = ws + 1572864;              // 393216
    ushort_t* Qb  = (ushort_t*)(ws + 1966080); // 196608 f
    ushort_t* Kb  = (ushort_t*)(ws + 2162688); // 196608 f
    ushort_t* Vt  = (ushort_t*)(ws + 2359296); // 196608 f
    float* ps     = ws + 2555904;              // 2*QS*4096 = 131072
    float* colinv = ws + 2686976;              // 8192
    ushort_t* xpart = (ushort_t*)(ws + 2695168); // bf16 (b,ks,q,48) = 3145728 f
    float* Y3     = ws + 5840896;              // (b,n,96) 786432
    ushort_t* Ypad= (ushort_t*)(ws + 6627328); // 559872 f
    ushort_t* wr  = (ushort_t*)(ws + 7187200); // 124416 f

    // conv3d weight repack (independent)
    w3_repack_kernel<<<972, 256, 0, stream>>>(w3, wr);
    // 1. positional encodings
    pe_add_kernel<<<1536, 256, 0, stream>>>(S, S_pe, 48, 16);
    pe_add_kernel<<<3072, 256, 0, stream>>>(Y, Y_pe, 96, 32);
    // conv3d input pad (bf16, halo zeroed inline)
    pad_build_kernel<<<1094, 256, 0, stream>>>(Y_pe, Ypad);
    // 2. projections (conv1x1 + BN + ReLU) -> (B,N,48), co-split x8
    proj_kernel<48><<<256, 256, 0, stream>>>(S_pe, w_s, b_s, g_s, be_s, S1);
    proj_kernel<96><<<256, 256, 0, stream>>>(Y_pe, w_y, b_y, g_y, be_y, Y1);
    // 3. Q, K row-major bf16; V transposed bf16, co-split x8
    qkv_kernel<<<768, 256, 0, stream>>>(Y1, S1, Wq, Wk, Wv, Qb, Kb, Vt);
    // 4. column exp-sum (softmax over q, per key k; no max — shift-invariant), MFMA
    attn_stats_mfma_kernel<<<BB * 16 * QS, 256, 0, stream>>>(Qb, Kb, ps);
    stats_reduce_kernel<<<64, 128, 0, stream>>>(ps, colinv);
    // 4b. pre-scale V by 1/Z (per key) so PV needs no colinv
    vscale_kernel<<<384, 256, 0, stream>>>(Vt, colinv);
    // 5. x = E @ V' partials, MFMA
    attn_pv_mfma_kernel<<<BB * 16 * KS, 256, 0, stream>>>(Qb, Kb, Vt, xpart);
    // 6. 3x3x3 conv branch, implicit-GEMM MFMA
    conv3d_mfma_kernel<<<768, 256, 0, stream>>>(Ypad, wr, b3, Y3);
    // 7. outputs, co-split x8
    z_out_kernel<<<256, 256, 0, stream>>>(xpart, w_o, b_o, g_o, be_o, S_pe, out);
    y2_out_kernel<<<256, 256, 0, stream>>>(Y3, w_y2, b_y2, g_y2, be_y2, out);
}

// Round 7
// 170.742 us; speedup vs baseline: 1.4900x; 1.1589x over previous
//
#include <hip/hip_runtime.h>
#include <hip/hip_bf16.h>

#define NPOS 4096
#define BB 2
#define KS 16  // k-split for PV pass (256 keys per chunk)
#define QS 16  // q-split for stats pass (256 q per chunk)

typedef short v4s __attribute__((ext_vector_type(4)));
typedef short v8s __attribute__((ext_vector_type(8)));
typedef float v4f __attribute__((ext_vector_type(4)));
typedef unsigned short ushort_t;

static __device__ __forceinline__ unsigned short f2bf(float f) {
    unsigned int u = __float_as_uint(f);
    return (unsigned short)((u + 0x7fffu + ((u >> 16) & 1u)) >> 16);
}
static __device__ __forceinline__ float bf2f(ushort_t s) {
    return __uint_as_float(((unsigned int)s) << 16);
}

__device__ __forceinline__ float pe_val(int C, int c, int ch, int h, int w) {
    int blk = ch / c;
    int j = ch - blk * c;
    int half = c >> 1;
    int jj = (j < half) ? j : j - half;
    float freq = __expf(-(2.0f * jj / (float)c) * 9.210340371976184f); // ln(10000)
    int pos = (blk < 2) ? h : w;   // torch-broadcast quirk: blocks 0,1 -> y(=h), block 2 -> z(=w)
    float s = (float)pos * freq;
    return (j < half) ? __sinf(s) : __cosf(s);
}

__global__ void pe_add_kernel(const float* __restrict__ in, float* __restrict__ out, int C, int c) {
    int idx = blockIdx.x * 256 + threadIdx.x;
    int total = BB * C * NPOS;
    if (idx >= total) return;
    int n = idx & 4095;
    int ch = (idx >> 12) % C;
    int h = (n >> 4) & 15;
    int w = n & 15;
    out[idx] = in[idx] + pe_val(C, c, ch, h, w);
}

// conv1x1 + BN + ReLU, co-split x8.  in: (B,CI,N) -> out: (B,N,48)
template<int CI>
__global__ void proj_kernel(const float* __restrict__ in, const float* __restrict__ w,
                            const float* __restrict__ bias, const float* __restrict__ g,
                            const float* __restrict__ be, float* __restrict__ out) {
    int pc = blockIdx.x >> 3, cc = blockIdx.x & 7;
    int o0 = cc * 6;
    __shared__ float wl[6 * CI];
    __shared__ float sb[6], bb[6];
    int t = threadIdx.x;
    for (int i = t; i < 6 * CI; i += 256) {
        int o = i / CI, ci = i - o * CI;
        wl[i] = w[(size_t)(o0 + o) * CI + ci];
    }
    if (t < 6) {
        float s = g[o0 + t] * rsqrtf(1.0f + 1e-5f);
        sb[t] = s; bb[t] = bias[o0 + t] * s + be[o0 + t];
    }
    __syncthreads();
    int gn = pc * 256 + t;
    int b = gn >> 12;
    const float* ip = in + (size_t)b * CI * NPOS + (gn & 4095);
    float acc[6];
#pragma unroll
    for (int o = 0; o < 6; o++) acc[o] = 0.f;
#pragma unroll
    for (int ci = 0; ci < CI; ci++) {
        float v = ip[(size_t)ci * NPOS];
#pragma unroll
        for (int o = 0; o < 6; o++) acc[o] += v * wl[o * CI + ci];
    }
    float* op = out + (size_t)gn * 48 + o0;
#pragma unroll
    for (int o = 0; o < 6; o++) {
        float z = acc[o] * sb[o] + bb[o];
        op[o] = z > 0.f ? z : 0.f;
    }
}

// Q,K,V co-split x8.  grid = 3 grp * 32 pc * 8 cc = 768 blocks.
__global__ void qkv_kernel(const float* __restrict__ Y1, const float* __restrict__ S1,
                           const float* __restrict__ Wq, const float* __restrict__ Wk,
                           const float* __restrict__ Wv, ushort_t* __restrict__ Qb,
                           ushort_t* __restrict__ Kb, ushort_t* __restrict__ Vt) {
    int grp = blockIdx.x >> 8;
    int r = blockIdx.x & 255;
    int pc = r >> 3, cc = r & 7;
    int o0 = cc * 6;
    const float* in = (grp == 2) ? S1 : Y1;
    const float* w = (grp == 0) ? Wq : (grp == 1) ? Wk : Wv;
    __shared__ float wl[48 * 6];   // [d][o]
    int t = threadIdx.x;
    for (int i = t; i < 48 * 6; i += 256) {
        int d = i / 6, o = i - d * 6;
        wl[i] = w[(size_t)d * 48 + o0 + o];
    }
    __syncthreads();
    int gn = pc * 256 + t;
    const float* ip = in + (size_t)gn * 48;
    float acc[6];
#pragma unroll
    for (int o = 0; o < 6; o++) acc[o] = 0.f;
#pragma unroll
    for (int d = 0; d < 48; d++) {
        float v = ip[d];
#pragma unroll
        for (int o = 0; o < 6; o++) acc[o] += v * wl[d * 6 + o];
    }
    if (grp < 2) {
        ushort_t* op = (grp == 0 ? Qb : Kb) + (size_t)gn * 48 + o0;
#pragma unroll
        for (int o = 0; o < 6; o++) op[o] = f2bf(acc[o]);
    } else {
        int b = gn >> 12; int n = gn & 4095;
#pragma unroll
        for (int o = 0; o < 6; o++)
            Vt[((size_t)(b * 48 + o0 + o) << 12) + n] = f2bf(acc[o]);
    }
}

// Pass 1: column (over-q) exp-sum.  Wave owns 64 keys (A-frags in regs),
// streams 256 q.  grid: b(2) x kb(16) x qs(16) = 512 blocks.
__global__ void attn_stats_mfma_kernel(const ushort_t* __restrict__ Qb,
                                       const ushort_t* __restrict__ Kb,
                                       float* __restrict__ ps) {
    int bid = blockIdx.x;
    int qs = bid & 15; int kb = (bid >> 4) & 15; int b = bid >> 8;
    int t = threadIdx.x; int wv = t >> 6; int lane = t & 63;
    int lr = lane & 15, g = lane >> 4;
    const float scale = 0.14433756729740643f;
    int key0 = kb * 256 + wv * 64;
    v4s ka[4][3];
#pragma unroll
    for (int kt = 0; kt < 4; kt++) {
        const ushort_t* krow = Kb + ((size_t)(b * NPOS + key0 + kt * 16 + lr)) * 48;
#pragma unroll
        for (int db = 0; db < 3; db++) ka[kt][db] = *(const v4s*)(krow + 16 * db + 4 * g);
    }
    float s[4][4];
#pragma unroll
    for (int kt = 0; kt < 4; kt++)
#pragma unroll
        for (int r = 0; r < 4; r++) s[kt][r] = 0.f;
    for (int qt = 0; qt < 16; qt++) {
        int q = qs * 256 + qt * 16 + lr;
        const ushort_t* qrow = Qb + ((size_t)(b * NPOS + q)) * 48;
        v4s qf0 = *(const v4s*)(qrow + 4 * g);
        v4s qf1 = *(const v4s*)(qrow + 16 + 4 * g);
        v4s qf2 = *(const v4s*)(qrow + 32 + 4 * g);
#pragma unroll
        for (int kt = 0; kt < 4; kt++) {
            v4f acc = {0.f, 0.f, 0.f, 0.f};
            acc = __builtin_amdgcn_mfma_f32_16x16x16bf16_1k(ka[kt][0], qf0, acc, 0, 0, 0);
            acc = __builtin_amdgcn_mfma_f32_16x16x16bf16_1k(ka[kt][1], qf1, acc, 0, 0, 0);
            acc = __builtin_amdgcn_mfma_f32_16x16x16bf16_1k(ka[kt][2], qf2, acc, 0, 0, 0);
#pragma unroll
            for (int r = 0; r < 4; r++) s[kt][r] += __expf(acc[r] * scale);
        }
    }
#pragma unroll
    for (int off = 1; off < 16; off <<= 1)
#pragma unroll
        for (int kt = 0; kt < 4; kt++)
#pragma unroll
            for (int r = 0; r < 4; r++) s[kt][r] += __shfl_xor(s[kt][r], off);
    if (lr == 0) {
#pragma unroll
        for (int kt = 0; kt < 4; kt++) {
            int idx = (b * QS + qs) * NPOS + key0 + kt * 16 + 4 * g;
            v4f ss = {s[kt][0], s[kt][1], s[kt][2], s[kt][3]};
            *(v4f*)&ps[idx] = ss;
        }
    }
}

__global__ void stats_reduce_kernel(const float* __restrict__ ps, float* __restrict__ colinv) {
    int idx = blockIdx.x * 128 + threadIdx.x;
    if (idx >= BB * NPOS) return;
    int b = idx >> 12; int k = idx & 4095;
    float s = 0.f;
#pragma unroll
    for (int qs = 0; qs < QS; qs++) s += ps[(size_t)(b * QS + qs) * NPOS + k];
    colinv[idx] = 1.0f / s;
}

// V' = V * colinv (per-key scale), in-place on Vt (b,48,4096).
__global__ void vscale_kernel(ushort_t* __restrict__ Vt, const float* __restrict__ colinv) {
    int idx = blockIdx.x * 256 + threadIdx.x;   // over B*48*1024
    if (idx >= BB * 48 * 1024) return;
    int n4 = idx & 1023; int rest = idx >> 10;
    int d = rest % 48; int b = rest / 48;
    ushort_t* vp = Vt + ((size_t)(b * 48 + d) << 12) + n4 * 4;
    v4s v = *(v4s*)vp;
    v4f ci = *(const v4f*)&colinv[(b << 12) + n4 * 4];
    v4s o;
#pragma unroll
    for (int j = 0; j < 4; j++) o[j] = (short)f2bf(bf2f((ushort_t)v[j]) * ci[j]);
    *(v4s*)vp = o;
}

// Pass 2: x = E * V' via MFMA (V pre-scaled by 1/Z).  Wave owns 64 q, streams
// 256 keys.  grid: b(2) x qb(16) x ks(16) = 512 blocks.  xpart bf16 (b,ks,q,48).
__global__ void attn_pv_mfma_kernel(const ushort_t* __restrict__ Qb,
                                    const ushort_t* __restrict__ Kb,
                                    const ushort_t* __restrict__ Vt,
                                    ushort_t* __restrict__ xpart) {
    int bid = blockIdx.x;
    int ks = bid & 15; int qb = (bid >> 4) & 15; int b = bid >> 8;
    int t = threadIdx.x; int wv = t >> 6; int lane = t & 63;
    int lr = lane & 15, g = lane >> 4;
    const float scale = 0.14433756729740643f;
    int q0 = qb * 256 + wv * 64;
    v4s qf[4][3];
#pragma unroll
    for (int qt = 0; qt < 4; qt++) {
        const ushort_t* qrow = Qb + ((size_t)(b * NPOS + q0 + qt * 16 + lr)) * 48;
#pragma unroll
        for (int db = 0; db < 3; db++) qf[qt][db] = *(const v4s*)(qrow + 16 * db + 4 * g);
    }
    v4f xacc[4][3];
#pragma unroll
    for (int qt = 0; qt < 4; qt++)
#pragma unroll
        for (int nt = 0; nt < 3; nt++) xacc[qt][nt] = (v4f){0.f, 0.f, 0.f, 0.f};
    for (int kt = 0; kt < 4; kt++) {
        int kb0 = ks * 256 + kt * 64;
        v4s p[4][4];   // [tm][qt]
#pragma unroll
        for (int tm = 0; tm < 4; tm++) {
            const ushort_t* krow = Kb + ((size_t)(b * NPOS + kb0 + 16 * tm + lr)) * 48;
            v4s ka0 = *(const v4s*)(krow + 4 * g);
            v4s ka1 = *(const v4s*)(krow + 16 + 4 * g);
            v4s ka2 = *(const v4s*)(krow + 32 + 4 * g);
#pragma unroll
            for (int qt = 0; qt < 4; qt++) {
                v4f acc = {0.f, 0.f, 0.f, 0.f};
                acc = __builtin_amdgcn_mfma_f32_16x16x16bf16_1k(ka0, qf[qt][0], acc, 0, 0, 0);
                acc = __builtin_amdgcn_mfma_f32_16x16x16bf16_1k(ka1, qf[qt][1], acc, 0, 0, 0);
                acc = __builtin_amdgcn_mfma_f32_16x16x16bf16_1k(ka2, qf[qt][2], acc, 0, 0, 0);
                v4s pp;
#pragma unroll
                for (int r = 0; r < 4; r++)
                    pp[r] = (short)f2bf(__expf(acc[r] * scale));
                p[tm][qt] = pp;
            }
        }
#pragma unroll
        for (int nt = 0; nt < 3; nt++) {
            const ushort_t* vrow = Vt + ((size_t)(b * 48 + 16 * nt + lr) << 12) + kb0;
#pragma unroll
            for (int tm = 0; tm < 4; tm++) {
                v4s vf = *(const v4s*)(vrow + 16 * tm + 4 * g);
#pragma unroll
                for (int qt = 0; qt < 4; qt++)
                    xacc[qt][nt] = __builtin_amdgcn_mfma_f32_16x16x16bf16_1k(
                        p[tm][qt], vf, xacc[qt][nt], 0, 0, 0);
            }
        }
    }
#pragma unroll
    for (int qt = 0; qt < 4; qt++)
#pragma unroll
        for (int nt = 0; nt < 3; nt++)
#pragma unroll
            for (int r = 0; r < 4; r++)
                xpart[(((size_t)(b * KS + ks) << 12) + q0 + qt * 16 + 4 * g + r) * 48 + 16 * nt + lr] =
                    f2bf(xacc[qt][nt][r]);
}

// Reduce x partials (bf16) + conv1x1(w_o) + BN + ReLU, * S_pe -> out ch [0,48).
__global__ void z_out_kernel(const ushort_t* __restrict__ xpart, const float* __restrict__ w_o,
                             const float* __restrict__ b_o, const float* __restrict__ g_o,
                             const float* __restrict__ be_o, const float* __restrict__ S_pe,
                             float* __restrict__ out) {
    int pc = blockIdx.x >> 3, cc = blockIdx.x & 7;
    int o0 = cc * 6;
    __shared__ float wl[6 * 48];
    __shared__ float sb[6], bb[6];
    int t = threadIdx.x;
    for (int i = t; i < 6 * 48; i += 256) {
        int o = i / 48, d = i - o * 48;
        wl[i] = w_o[(size_t)(o0 + o) * 48 + d];
    }
    if (t < 6) {
        float s = g_o[o0 + t] * rsqrtf(1.f + 1e-5f);
        sb[t] = s; bb[t] = b_o[o0 + t] * s + be_o[o0 + t];
    }
    __syncthreads();
    int gn = pc * 256 + t;
    int b = gn >> 12; int n = gn & 4095;
    float x[48];
#pragma unroll
    for (int d = 0; d < 48; d++) x[d] = 0.f;
#pragma unroll
    for (int ks = 0; ks < KS; ks++) {
        const v4s* p = (const v4s*)(xpart + (((size_t)(b * KS + ks) << 12) + n) * 48);
#pragma unroll
        for (int d4 = 0; d4 < 12; d4++) {
            v4s v = p[d4];
#pragma unroll
            for (int j = 0; j < 4; j++) x[d4 * 4 + j] += bf2f((ushort_t)v[j]);
        }
    }
#pragma unroll
    for (int o = 0; o < 6; o++) {
        float acc = 0.f;
#pragma unroll
        for (int d = 0; d < 48; d++) acc += wl[o * 48 + d] * x[d];
        float z = acc * sb[o] + bb[o];
        z = z > 0.f ? z : 0.f;
        out[((size_t)b * 96 + o0 + o) * NPOS + n] = z * S_pe[((size_t)b * 48 + o0 + o) * NPOS + n];
    }
}

// ---- conv3d via implicit-GEMM MFMA ----

// Y_pe (B,96,4096) fp32 -> Y_pad (B,18,18,18,96) bf16, halo zeroed inline
__global__ void pad_build_kernel(const float* __restrict__ Y_pe, ushort_t* __restrict__ Ypad) {
    int idx = blockIdx.x * 256 + threadIdx.x;   // over B*5832 cells * 24 ci4
    if (idx >= BB * 5832 * 24) return;
    int ci4 = idx % 24;
    int cell = idx / 24;
    int wp = cell % 18; int c2 = cell / 18;
    int hp = c2 % 18; int c3 = c2 / 18;
    int zp = c3 % 18; int b = c3 / 18;
    ushort_t pk[4] = {0, 0, 0, 0};
    if (zp >= 1 && zp <= 16 && hp >= 1 && hp <= 16 && wp >= 1 && wp <= 16) {
        int n = (zp - 1) * 256 + (hp - 1) * 16 + (wp - 1);
#pragma unroll
        for (int j = 0; j < 4; j++)
            pk[j] = f2bf(Y_pe[((size_t)(b * 96 + ci4 * 4 + j) << 12) + n]);
    }
    *(v4s*)&Ypad[(size_t)idx * 4] = *(v4s*)pk;
}

// w3 (96co, 96ci, 27tap) fp32 -> wr [27][96co][96ci] bf16
__global__ void w3_repack_kernel(const float* __restrict__ w3, ushort_t* __restrict__ wr) {
    int idx = blockIdx.x * 256 + threadIdx.x;
    if (idx >= 27 * 96 * 96) return;
    int ci = idx % 96;
    int t2 = idx / 96;
    int co = t2 % 96;
    int tap = t2 / 96;
    wr[idx] = f2bf(w3[(size_t)(co * 96 + ci) * 27 + tap]);
}

// implicit-GEMM conv, 16x16x32 MFMA (K=32; ci=96=3x32).  3 independent acc
// chains (per kd) + explicit (kd,kh)-burst register staging for load ILP.
// Y3 out layout: position-major (B,4096,96) fp32.
__global__ __launch_bounds__(256, 2)
void conv3d_mfma_kernel(const ushort_t* __restrict__ Ypad,
                        const ushort_t* __restrict__ wr,
                        const float* __restrict__ b3,
                        float* __restrict__ Y3) {
    int bid = blockIdx.x;
    int b = bid / 384;
    int r = bid % 384;
    int cot = r % 6;
    int zhq = r / 6;                 // 0..63
    int t = threadIdx.x; int wv = t >> 6; int lane = t & 63;
    int z = zhq >> 2;
    int h = (zhq & 3) * 4 + wv;
    int lr = lane & 15, g = lane >> 4;
    v4f acc[3];
#pragma unroll
    for (int kd = 0; kd < 3; kd++) acc[kd] = (v4f){0.f, 0.f, 0.f, 0.f};
    const ushort_t* wbase = wr + (size_t)(cot * 16 + lr) * 96 + 8 * g;
#pragma unroll
    for (int kd = 0; kd < 3; kd++) {
#pragma unroll
        for (int kh = 0; kh < 3; kh++) {
            const ushort_t* arow = Ypad + (((size_t)(b * 18 + z + kd) * 18 + h + kh) * 18 + lr) * 96 + 8 * g;
            int tap0 = (kd * 3 + kh) * 3;
            v8s af[3][3], bf[3][3];
#pragma unroll
            for (int kw = 0; kw < 3; kw++)
#pragma unroll
                for (int c = 0; c < 3; c++) {
                    af[kw][c] = *(const v8s*)(arow + kw * 96 + c * 32);
                    bf[kw][c] = *(const v8s*)(wbase + (size_t)(tap0 + kw) * 96 * 96 + c * 32);
                }
#pragma unroll
            for (int kw = 0; kw < 3; kw++)
#pragma unroll
                for (int c = 0; c < 3; c++)
                    acc[kd] = __builtin_amdgcn_mfma_f32_16x16x32_bf16(
                        af[kw][c], bf[kw][c], acc[kd], 0, 0, 0);
        }
    }
    float bv = b3[cot * 16 + lr];
    int pos = z * 256 + h * 16 + 4 * g;
#pragma unroll
    for (int r2 = 0; r2 < 4; r2++)
        Y3[(((size_t)b << 12) + pos + r2) * 96 + cot * 16 + lr] =
            acc[0][r2] + acc[1][r2] + acc[2][r2] + bv;
}

// conv1x1(w_y2) + BN + ReLU on Y3 (B,4096,96) -> out ch [48,96).  co-split x8.
__global__ void y2_out_kernel(const float* __restrict__ Y3, const float* __restrict__ w_y2,
                              const float* __restrict__ b_y2, const float* __restrict__ g_y2,
                              const float* __restrict__ be_y2, float* __restrict__ out) {
    int pc = blockIdx.x >> 3, cc = blockIdx.x & 7;
    int o0 = cc * 6;
    __shared__ float wl[6 * 96];
    __shared__ float sb[6], bb[6];
    int t = threadIdx.x;
    for (int i = t; i < 6 * 96; i += 256) {
        int o = i / 96, ci = i - o * 96;
        wl[i] = w_y2[(size_t)(o0 + o) * 96 + ci];
    }
    if (t < 6) {
        float s = g_y2[o0 + t] * rsqrtf(1.f + 1e-5f);
        sb[t] = s; bb[t] = b_y2[o0 + t] * s + be_y2[o0 + t];
    }
    __syncthreads();
    int gn = pc * 256 + t;
    int b = gn >> 12; int n = gn & 4095;
    const v4f* ip = (const v4f*)(Y3 + (size_t)gn * 96);
    float acc[6];
#pragma unroll
    for (int o = 0; o < 6; o++) acc[o] = 0.f;
#pragma unroll
    for (int c4 = 0; c4 < 24; c4++) {
        v4f v = ip[c4];
#pragma unroll
        for (int j = 0; j < 4; j++)
#pragma unroll
            for (int o = 0; o < 6; o++) acc[o] += v[j] * wl[o * 96 + c4 * 4 + j];
    }
#pragma unroll
    for (int o = 0; o < 6; o++) {
        float z = acc[o] * sb[o] + bb[o];
        out[((size_t)b * 96 + 48 + o0 + o) * NPOS + n] = z > 0.f ? z : 0.f;
    }
}

extern "C" void kernel_launch(void* const* d_in, const int* in_sizes, int n_in,
                              void* d_out, int out_size, void* d_ws, size_t ws_size,
                              hipStream_t stream) {
    const float* Y    = (const float*)d_in[0];
    const float* S    = (const float*)d_in[1];
    const float* w_s  = (const float*)d_in[2];
    const float* b_s  = (const float*)d_in[3];
    const float* g_s  = (const float*)d_in[4];
    const float* be_s = (const float*)d_in[5];
    const float* w_y  = (const float*)d_in[6];
    const float* b_y  = (const float*)d_in[7];
    const float* g_y  = (const float*)d_in[8];
    const float* be_y = (const float*)d_in[9];
    const float* Wq   = (const float*)d_in[10];
    const float* Wk   = (const float*)d_in[11];
    const float* Wv   = (const float*)d_in[12];
    const float* w_o  = (const float*)d_in[13];
    const float* b_o  = (const float*)d_in[14];
    const float* g_o  = (const float*)d_in[15];
    const float* be_o = (const float*)d_in[16];
    const float* w3   = (const float*)d_in[17];
    const float* b3   = (const float*)d_in[18];
    const float* w_y2 = (const float*)d_in[19];
    const float* b_y2 = (const float*)d_in[20];
    const float* g_y2 = (const float*)d_in[21];
    const float* be_y2= (const float*)d_in[22];
    float* out = (float*)d_out;

    float* ws = (float*)d_ws;
    float* S_pe   = ws;                        // 393216
    float* Y_pe   = ws + 393216;               // 786432
    float* S1     = ws + 1179648;              // 393216
    float* Y1     = ws + 1572864;              // 393216
    ushort_t* Qb  = (ushort_t*)(ws + 1966080); // 196608 f
    ushort_t* Kb  = (ushort_t*)(ws + 2162688); // 196608 f
    ushort_t* Vt  = (ushort_t*)(ws + 2359296); // 196608 f
    float* ps     = ws + 2555904;              // 2*QS*4096 = 131072
    float* colinv = ws + 2686976;              // 8192
    ushort_t* xpart = (ushort_t*)(ws + 2695168); // bf16 (b,ks,q,48) = 3145728 f
    float* Y3     = ws + 5840896;              // (b,n,96) 786432
    ushort_t* Ypad= (ushort_t*)(ws + 6627328); // 559872 f
    ushort_t* wr  = (ushort_t*)(ws + 7187200); // 124416 f

    // conv3d weight repack (independent)
    w3_repack_kernel<<<972, 256, 0, stream>>>(w3, wr);
    // 1. positional encodings
    pe_add_kernel<<<1536, 256, 0, stream>>>(S, S_pe, 48, 16);
    pe_add_kernel<<<3072, 256, 0, stream>>>(Y, Y_pe, 96, 32);
    // conv3d input pad (bf16, halo zeroed inline)
    pad_build_kernel<<<1094, 256, 0, stream>>>(Y_pe, Ypad);
    // 2. projections (conv1x1 + BN + ReLU) -> (B,N,48), co-split x8
    proj_kernel<48><<<256, 256, 0, stream>>>(S_pe, w_s, b_s, g_s, be_s, S1);
    proj_kernel<96><<<256, 256, 0, stream>>>(Y_pe, w_y, b_y, g_y, be_y, Y1);
    // 3. Q, K row-major bf16; V transposed bf16, co-split x8
    qkv_kernel<<<768, 256, 0, stream>>>(Y1, S1, Wq, Wk, Wv, Qb, Kb, Vt);
    // 4. column exp-sum (softmax over q, per key k; no max — shift-invariant), MFMA
    attn_stats_mfma_kernel<<<BB * 16 * QS, 256, 0, stream>>>(Qb, Kb, ps);
    stats_reduce_kernel<<<64, 128, 0, stream>>>(ps, colinv);
    // 4b. pre-scale V by 1/Z (per key) so PV needs no colinv
    vscale_kernel<<<384, 256, 0, stream>>>(Vt, colinv);
    // 5. x = E @ V' partials, MFMA
    attn_pv_mfma_kernel<<<BB * 16 * KS, 256, 0, stream>>>(Qb, Kb, Vt, xpart);
    // 6. 3x3x3 conv branch, implicit-GEMM MFMA (16x16x32)
    conv3d_mfma_kernel<<<768, 256, 0, stream>>>(Ypad, wr, b3, Y3);
    // 7. outputs, co-split x8
    z_out_kernel<<<256, 256, 0, stream>>>(xpart, w_o, b_o, g_o, be_o, S_pe, out);
    y2_out_kernel<<<256, 256, 0, stream>>>(Y3, w_y2, b_y2, g_y2, be_y2, out);
}